// Round 6
// baseline (341.593 us; speedup 1.0000x reference)
//
#include <hip/hip_runtime.h>
#include <hip/hip_fp16.h>

// Guided filter, B=4 H=1024 W=1024 C=4 f32 NHWC, r from d_in[2] (expected 40).
// Fused per box-pass. R5->R6: the kernel is MLP/latency-bound (occupancy 10.6%
// = 1 block/CU, HBM 2.5 TB/s). Changes:
//  - BH 16->8: grid 512 blocks = 2 blocks/CU (LDS 74KB x2 = 148 <= 160 KB).
//  - __launch_bounds__(256,2).
//  - XCD-aware band swizzle: consecutive bands (overlapping warm-up windows,
//    read concurrently at kernel start) land on the same XCD's L2.
//  - warm-up batched 4 rows deep (32 float4 in flight) for MLP.
// kfusedAB: I,p -> vertical sliding sums {I,p,Ip,II} in registers; per row a
//           block-wide prefix scan (swizzled LDS planes) -> horizontal box;
//           A,b out (fp16).
// kfusedQ : same over {A,b}; q = meanA*I + meanb -> d_out (f32).
// N = cntH(h)*cntW(w) analytic.

#define HD 1024
#define WD 1024
#define ROW4 WD                      // float4 pixels per row
#define IMG4 ((size_t)HD * ROW4)     // pixels per image
#define IMGF (IMG4 * 4)              // floats per image
#define BH 8                         // output rows per block
#define NB (HD / BH)                 // 128 bands
#define EPS 1e-8f
#define PFXN 1153                    // idx4(1024) = 1152, +1

__device__ __forceinline__ int idx4(int p) { return p + (p >> 3); }

struct H4 { __half2 lo, hi; };       // one fp16 pixel (4 channels)

__device__ __forceinline__ H4 pack4(float4 v) {
    H4 h; h.lo = __floats2half2_rn(v.x, v.y); h.hi = __floats2half2_rn(v.z, v.w);
    return h;
}
__device__ __forceinline__ float4 unpack4(H4 h) {
    float2 l = __half22float2(h.lo), u = __half22float2(h.hi);
    return make_float4(l.x, l.y, u.x, u.y);
}
__device__ __forceinline__ float4 f4add(float4 a, float4 b) {
    return make_float4(a.x + b.x, a.y + b.y, a.z + b.z, a.w + b.w);
}
__device__ __forceinline__ float4 f4sub(float4 a, float4 b) {
    return make_float4(a.x - b.x, a.y - b.y, a.z - b.z, a.w - b.w);
}
__device__ __forceinline__ float4 f4s(float4 a, float s) {
    return make_float4(a.x * s, a.y * s, a.z * s, a.w * s);
}
__device__ __forceinline__ float4 f4mul(float4 a, float4 b) {
    return make_float4(a.x * b.x, a.y * b.y, a.z * b.z, a.w * b.w);
}
__device__ __forceinline__ float4 shup4(float4 v, int d) {
    return make_float4(__shfl_up(v.x, d), __shfl_up(v.y, d), __shfl_up(v.z, d), __shfl_up(v.w, d));
}
// XCD-grouping band swizzle: blocks with equal (bx%8) dispatch to the same
// XCD; give them consecutive bands. Bijective since NB % 8 == 0.
__device__ __forceinline__ int band_of(int bx, int nbands) {
    return (bx & 7) * (nbands >> 3) + (bx >> 3);
}

// Block-wide inclusive prefix of 4 fields into swizzled planes pl[f][idx4(p)],
// pl[f][idx4(0)] = 0. 2 internal syncs; 1 more needed after consumption.
__device__ __forceinline__ void scan4(
    float4 (*pl)[PFXN], float4 (*wtot)[4],
    const float4* s0, const float4* s1, const float4* s2, const float4* s3,
    int t, int lane, int wv)
{
    const float4 z4 = make_float4(0.f, 0.f, 0.f, 0.f);
    float4 p0[4], p1[4], p2[4], p3[4];
    p0[0] = s0[0]; p1[0] = s1[0]; p2[0] = s2[0]; p3[0] = s3[0];
    #pragma unroll
    for (int i = 1; i < 4; ++i) {
        p0[i] = f4add(p0[i-1], s0[i]); p1[i] = f4add(p1[i-1], s1[i]);
        p2[i] = f4add(p2[i-1], s2[i]); p3[i] = f4add(p3[i-1], s3[i]);
    }
    float4 i0 = p0[3], i1 = p1[3], i2 = p2[3], i3 = p3[3];
    #pragma unroll
    for (int d = 1; d < 64; d <<= 1) {
        float4 t0 = shup4(i0, d), t1 = shup4(i1, d), t2 = shup4(i2, d), t3 = shup4(i3, d);
        if (lane >= d) {
            i0 = f4add(i0, t0); i1 = f4add(i1, t1);
            i2 = f4add(i2, t2); i3 = f4add(i3, t3);
        }
    }
    float4 e0 = shup4(i0, 1), e1 = shup4(i1, 1), e2 = shup4(i2, 1), e3 = shup4(i3, 1);
    if (lane == 0) { e0 = z4; e1 = z4; e2 = z4; e3 = z4; }
    if (lane == 63) { wtot[wv][0] = i0; wtot[wv][1] = i1; wtot[wv][2] = i2; wtot[wv][3] = i3; }
    __syncthreads();
    for (int wq = 0; wq < wv; ++wq) {
        e0 = f4add(e0, wtot[wq][0]); e1 = f4add(e1, wtot[wq][1]);
        e2 = f4add(e2, wtot[wq][2]); e3 = f4add(e3, wtot[wq][3]);
    }
    if (t == 0) {
        pl[0][idx4(0)] = z4; pl[1][idx4(0)] = z4;
        pl[2][idx4(0)] = z4; pl[3][idx4(0)] = z4;
    }
    #pragma unroll
    for (int i = 0; i < 4; ++i) {
        int p = 4 * t + 1 + i;
        pl[0][idx4(p)] = f4add(e0, p0[i]);
        pl[1][idx4(p)] = f4add(e1, p1[i]);
        pl[2][idx4(p)] = f4add(e2, p2[i]);
        pl[3][idx4(p)] = f4add(e3, p3[i]);
    }
    __syncthreads();
}

// Same for 2 fields.
__device__ __forceinline__ void scan2s(
    float4 (*pl)[PFXN], float4 (*wtot)[2],
    const float4* s0, const float4* s1, int t, int lane, int wv)
{
    const float4 z4 = make_float4(0.f, 0.f, 0.f, 0.f);
    float4 p0[4], p1[4];
    p0[0] = s0[0]; p1[0] = s1[0];
    #pragma unroll
    for (int i = 1; i < 4; ++i) {
        p0[i] = f4add(p0[i-1], s0[i]); p1[i] = f4add(p1[i-1], s1[i]);
    }
    float4 i0 = p0[3], i1 = p1[3];
    #pragma unroll
    for (int d = 1; d < 64; d <<= 1) {
        float4 t0 = shup4(i0, d), t1 = shup4(i1, d);
        if (lane >= d) { i0 = f4add(i0, t0); i1 = f4add(i1, t1); }
    }
    float4 e0 = shup4(i0, 1), e1 = shup4(i1, 1);
    if (lane == 0) { e0 = z4; e1 = z4; }
    if (lane == 63) { wtot[wv][0] = i0; wtot[wv][1] = i1; }
    __syncthreads();
    for (int wq = 0; wq < wv; ++wq) {
        e0 = f4add(e0, wtot[wq][0]); e1 = f4add(e1, wtot[wq][1]);
    }
    if (t == 0) { pl[0][idx4(0)] = z4; pl[1][idx4(0)] = z4; }
    #pragma unroll
    for (int i = 0; i < 4; ++i) {
        int p = 4 * t + 1 + i;
        pl[0][idx4(p)] = f4add(e0, p0[i]);
        pl[1][idx4(p)] = f4add(e1, p1[i]);
    }
    __syncthreads();
}

// ---------------- KA: I,p -> A,b (fp16) ----------------
__global__ __launch_bounds__(256, 2) void kfusedAB(
    const float4* __restrict__ I4, const float4* __restrict__ P4,
    H4* __restrict__ Aout, H4* __restrict__ Bout,
    const int* __restrict__ rptr)
{
    __shared__ float4 Pfx[4][PFXN];       // 73.8 KB, swizzled planes
    __shared__ float4 wtot[4][4];
    const int r = *rptr;
    const int t = threadIdx.x, lane = t & 63, wv = t >> 6;
    const int h0 = band_of(blockIdx.x, gridDim.x) * BH;
    const size_t imgb = (size_t)blockIdx.y * IMG4;
    const float4* Ib = I4 + imgb + 4 * t;
    const float4* Pb = P4 + imgb + 4 * t;
    H4* Ao = Aout + imgb;
    H4* Bo = Bout + imgb;
    const float4 z4 = make_float4(0.f, 0.f, 0.f, 0.f);

    float4 sI[4], sp[4], sIp[4], sII[4];
    #pragma unroll
    for (int i = 0; i < 4; ++i) { sI[i] = z4; sp[i] = z4; sIp[i] = z4; sII[i] = z4; }

    int lo = h0 - r; if (lo < 0) lo = 0;
    int hi = h0 + r; if (hi > HD - 1) hi = HD - 1;
    // warm-up, 4 rows batched for MLP
    int j = lo;
    for (; j + 3 <= hi; j += 4) {
        float4 a[4][4], c[4][4];
        #pragma unroll
        for (int k = 0; k < 4; ++k) {
            const float4* Ir = Ib + (size_t)(j + k) * ROW4;
            const float4* Pr = Pb + (size_t)(j + k) * ROW4;
            #pragma unroll
            for (int i = 0; i < 4; ++i) { a[k][i] = Ir[i]; c[k][i] = Pr[i]; }
        }
        #pragma unroll
        for (int k = 0; k < 4; ++k)
            #pragma unroll
            for (int i = 0; i < 4; ++i) {
                sI[i] = f4add(sI[i], a[k][i]);
                sp[i] = f4add(sp[i], c[k][i]);
                sIp[i].x += a[k][i].x * c[k][i].x; sIp[i].y += a[k][i].y * c[k][i].y;
                sIp[i].z += a[k][i].z * c[k][i].z; sIp[i].w += a[k][i].w * c[k][i].w;
                sII[i].x += a[k][i].x * a[k][i].x; sII[i].y += a[k][i].y * a[k][i].y;
                sII[i].z += a[k][i].z * a[k][i].z; sII[i].w += a[k][i].w * a[k][i].w;
            }
    }
    for (; j <= hi; ++j) {
        const float4* Ir = Ib + (size_t)j * ROW4;
        const float4* Pr = Pb + (size_t)j * ROW4;
        #pragma unroll
        for (int i = 0; i < 4; ++i) {
            float4 a = Ir[i], c = Pr[i];
            sI[i] = f4add(sI[i], a); sp[i] = f4add(sp[i], c);
            sIp[i].x += a.x*c.x; sIp[i].y += a.y*c.y; sIp[i].z += a.z*c.z; sIp[i].w += a.w*c.w;
            sII[i].x += a.x*a.x; sII[i].y += a.y*a.y; sII[i].z += a.z*a.z; sII[i].w += a.w*a.w;
        }
    }

    for (int h = h0; h < h0 + BH; ++h) {
        int hl = h - r; if (hl < 0) hl = 0;
        int hh = h + r; if (hh > HD - 1) hh = HD - 1;
        const float cntH = (float)(hh - hl + 1);

        // early-issue slide rows (consumed at end of iteration)
        int ja = h + 1 + r, js = h - r;
        float wa  = (ja <= HD - 1) ? 1.f : 0.f;
        float wsb = (js >= 0) ? 1.f : 0.f;
        int jac = (ja <= HD - 1) ? ja : HD - 1;
        int jsc = (js >= 0) ? js : 0;
        const float4* Iar = Ib + (size_t)jac * ROW4;
        const float4* Par = Pb + (size_t)jac * ROW4;
        const float4* Isr = Ib + (size_t)jsc * ROW4;
        const float4* Psr = Pb + (size_t)jsc * ROW4;
        float4 a1[4], c1[4], a2[4], c2[4];
        #pragma unroll
        for (int i = 0; i < 4; ++i) { a1[i] = Iar[i]; c1[i] = Par[i]; a2[i] = Isr[i]; c2[i] = Psr[i]; }

        scan4(Pfx, wtot, sI, sp, sIp, sII, t, lane, wv);

        H4* Ar = Ao + (size_t)h * ROW4;
        H4* Br = Bo + (size_t)h * ROW4;
        #pragma unroll
        for (int i = 0; i < 4; ++i) {
            int wp = 4 * t + i;
            int wl = wp - r; if (wl < 0) wl = 0;
            int wh2 = wp + r; if (wh2 > WD - 1) wh2 = WD - 1;
            float invN = 1.f / ((float)(wh2 - wl + 1) * cntH);
            int iA = idx4(wh2 + 1), iB = idx4(wl);
            float4 mI  = f4s(f4sub(Pfx[0][iA], Pfx[0][iB]), invN);
            float4 mp  = f4s(f4sub(Pfx[1][iA], Pfx[1][iB]), invN);
            float4 mIp = f4s(f4sub(Pfx[2][iA], Pfx[2][iB]), invN);
            float4 mII = f4s(f4sub(Pfx[3][iA], Pfx[3][iB]), invN);
            float4 cov = f4sub(mIp, f4mul(mI, mp));
            float4 var = f4sub(mII, f4mul(mI, mI));
            float4 Av = make_float4(cov.x / (var.x + EPS), cov.y / (var.y + EPS),
                                    cov.z / (var.z + EPS), cov.w / (var.w + EPS));
            float4 Bv = f4sub(mp, f4mul(Av, mI));
            Ar[wp] = pack4(Av);
            Br[wp] = pack4(Bv);
        }
        __syncthreads();

        // slide window h -> h+1
        #pragma unroll
        for (int i = 0; i < 4; ++i) {
            float4 A1 = f4s(a1[i], wa),  C1 = f4s(c1[i], wa);
            float4 A2 = f4s(a2[i], wsb), C2 = f4s(c2[i], wsb);
            sI[i] = f4add(f4sub(sI[i], A2), A1);
            sp[i] = f4add(f4sub(sp[i], C2), C1);
            sIp[i].x += A1.x*C1.x - A2.x*C2.x; sIp[i].y += A1.y*C1.y - A2.y*C2.y;
            sIp[i].z += A1.z*C1.z - A2.z*C2.z; sIp[i].w += A1.w*C1.w - A2.w*C2.w;
            sII[i].x += A1.x*A1.x - A2.x*A2.x; sII[i].y += A1.y*A1.y - A2.y*A2.y;
            sII[i].z += A1.z*A1.z - A2.z*A2.z; sII[i].w += A1.w*A1.w - A2.w*A2.w;
        }
    }
}

// ---------------- KB: A,b -> q = meanA*I + meanb ----------------
__global__ __launch_bounds__(256, 2) void kfusedQ(
    const H4* __restrict__ Ain, const H4* __restrict__ Bin,
    const float4* __restrict__ I4, float4* __restrict__ Qout,
    const int* __restrict__ rptr)
{
    __shared__ float4 Pfx[2][PFXN];       // 36.9 KB
    __shared__ float4 wtot[4][2];
    const int r = *rptr;
    const int t = threadIdx.x, lane = t & 63, wv = t >> 6;
    const int h0 = band_of(blockIdx.x, gridDim.x) * BH;
    const size_t imgb = (size_t)blockIdx.y * IMG4;
    const H4* Abp = Ain + imgb + 4 * t;
    const H4* Bbp = Bin + imgb + 4 * t;
    const float4* Ib = I4 + imgb + 4 * t;
    float4* Qo = Qout + imgb;
    const float4 z4 = make_float4(0.f, 0.f, 0.f, 0.f);

    float4 sA[4], sB[4];
    #pragma unroll
    for (int i = 0; i < 4; ++i) { sA[i] = z4; sB[i] = z4; }

    int lo = h0 - r; if (lo < 0) lo = 0;
    int hi = h0 + r; if (hi > HD - 1) hi = HD - 1;
    // warm-up, 4 rows batched
    int j = lo;
    for (; j + 3 <= hi; j += 4) {
        H4 a[4][4], b[4][4];
        #pragma unroll
        for (int k = 0; k < 4; ++k) {
            const H4* Ar = Abp + (size_t)(j + k) * ROW4;
            const H4* Br = Bbp + (size_t)(j + k) * ROW4;
            #pragma unroll
            for (int i = 0; i < 4; ++i) { a[k][i] = Ar[i]; b[k][i] = Br[i]; }
        }
        #pragma unroll
        for (int k = 0; k < 4; ++k)
            #pragma unroll
            for (int i = 0; i < 4; ++i) {
                sA[i] = f4add(sA[i], unpack4(a[k][i]));
                sB[i] = f4add(sB[i], unpack4(b[k][i]));
            }
    }
    for (; j <= hi; ++j) {
        const H4* Ar = Abp + (size_t)j * ROW4;
        const H4* Br = Bbp + (size_t)j * ROW4;
        #pragma unroll
        for (int i = 0; i < 4; ++i) {
            sA[i] = f4add(sA[i], unpack4(Ar[i]));
            sB[i] = f4add(sB[i], unpack4(Br[i]));
        }
    }

    for (int h = h0; h < h0 + BH; ++h) {
        int hl = h - r; if (hl < 0) hl = 0;
        int hh = h + r; if (hh > HD - 1) hh = HD - 1;
        const float cntH = (float)(hh - hl + 1);

        // early-issue slide rows + I row
        int ja = h + 1 + r, js = h - r;
        float wa  = (ja <= HD - 1) ? 1.f : 0.f;
        float wsb = (js >= 0) ? 1.f : 0.f;
        int jac = (ja <= HD - 1) ? ja : HD - 1;
        int jsc = (js >= 0) ? js : 0;
        const H4* Aar = Abp + (size_t)jac * ROW4;
        const H4* Bar = Bbp + (size_t)jac * ROW4;
        const H4* Asr = Abp + (size_t)jsc * ROW4;
        const H4* Bsr = Bbp + (size_t)jsc * ROW4;
        const float4* Irow = Ib + (size_t)h * ROW4;
        H4 a1[4], b1[4], a2[4], b2[4];
        float4 iv[4];
        #pragma unroll
        for (int i = 0; i < 4; ++i) {
            a1[i] = Aar[i]; b1[i] = Bar[i];
            a2[i] = Asr[i]; b2[i] = Bsr[i];
            iv[i] = Irow[i];
        }

        scan2s(Pfx, wtot, sA, sB, t, lane, wv);

        float4* Qrow = Qo + (size_t)h * ROW4;
        #pragma unroll
        for (int i = 0; i < 4; ++i) {
            int wp = 4 * t + i;
            int wl = wp - r; if (wl < 0) wl = 0;
            int wh2 = wp + r; if (wh2 > WD - 1) wh2 = WD - 1;
            float invN = 1.f / ((float)(wh2 - wl + 1) * cntH);
            int iA = idx4(wh2 + 1), iB = idx4(wl);
            float4 mA = f4s(f4sub(Pfx[0][iA], Pfx[0][iB]), invN);
            float4 mB = f4s(f4sub(Pfx[1][iA], Pfx[1][iB]), invN);
            Qrow[wp] = make_float4(mA.x * iv[i].x + mB.x, mA.y * iv[i].y + mB.y,
                                   mA.z * iv[i].z + mB.z, mA.w * iv[i].w + mB.w);
        }
        __syncthreads();

        // slide
        #pragma unroll
        for (int i = 0; i < 4; ++i) {
            float4 A1 = f4s(unpack4(a1[i]), wa),  B1 = f4s(unpack4(b1[i]), wa);
            float4 A2 = f4s(unpack4(a2[i]), wsb), B2 = f4s(unpack4(b2[i]), wsb);
            sA[i] = f4add(f4sub(sA[i], A2), A1);
            sB[i] = f4add(f4sub(sB[i], B2), B1);
        }
    }
}

extern "C" void kernel_launch(void* const* d_in, const int* in_sizes, int n_in,
                              void* d_out, int out_size, void* d_ws, size_t ws_size,
                              hipStream_t stream)
{
    const float* I = (const float*)d_in[0];
    const float* P = (const float*)d_in[1];
    const int* rptr = (const int*)d_in[2];
    float* out = (float*)d_out;

    const int Bn = (int)(in_sizes[0] / IMGF);              // 4
    const size_t perBatch = 2 * IMG4 * sizeof(H4);         // A,b fp16 = 16 MiB

    int nbChunk = (int)(ws_size / perBatch);
    if (nbChunk < 1) nbChunk = 1;
    if (nbChunk > Bn) nbChunk = Bn;

    for (int b0 = 0; b0 < Bn; b0 += nbChunk) {
        const int nb = (b0 + nbChunk <= Bn) ? nbChunk : (Bn - b0);
        H4* Ah = (H4*)d_ws;
        H4* Bh = Ah + (size_t)nb * IMG4;
        const float4* Ib = (const float4*)(I + (size_t)b0 * IMGF);
        const float4* Pb = (const float4*)(P + (size_t)b0 * IMGF);
        float4* ob = (float4*)(out + (size_t)b0 * IMGF);

        kfusedAB<<<dim3(NB, nb), 256, 0, stream>>>(Ib, Pb, Ah, Bh, rptr);
        kfusedQ<<<dim3(NB, nb), 256, 0, stream>>>(Ah, Bh, Ib, ob, rptr);
    }
}

// Round 7
// 281.171 us; speedup vs baseline: 1.2149x; 1.2149x over previous
//
#include <hip/hip_runtime.h>
#include <hip/hip_fp16.h>

// Guided filter, B=4 H=1024 W=1024 C=4 f32 NHWC, r from d_in[2] (expected 40).
// Fused per box-pass. R6->R7: R6's BH=8 doubled warm-up read amplification
// (FETCH 452->700 MB) and regressed. Revert to BH=16 and instead get 8
// waves/CU via 512-thread blocks (2 float4 pixels/thread, grid still
// 256 blocks = 1/CU). Steady state processes output rows in PAIRS with all
// 4 slide rows' loads issued up front (2x MLP).
// kfusedAB: I,p -> vertical sliding sums {I,p,Ip,II} in registers; per row a
//           block-wide prefix scan (swizzled LDS planes) -> horizontal box;
//           A,b out (fp16).
// kfusedQ : same over {A,b}; q = meanA*I + meanb -> d_out (f32).
// N = cntH(h)*cntW(w) analytic.

#define HD 1024
#define WD 1024
#define ROW4 WD                      // float4 pixels per row
#define IMG4 ((size_t)HD * ROW4)     // pixels per image
#define IMGF (IMG4 * 4)              // floats per image
#define BH 16                        // output rows per block
#define NB (HD / BH)                 // 64 bands
#define TPB 512                      // threads per block (8 waves)
#define EPS 1e-8f
#define PFXN 1153                    // idx4(1024) = 1152, +1

__device__ __forceinline__ int idx4(int p) { return p + (p >> 3); }

struct H4 { __half2 lo, hi; };       // one fp16 pixel (4 channels)

__device__ __forceinline__ H4 pack4(float4 v) {
    H4 h; h.lo = __floats2half2_rn(v.x, v.y); h.hi = __floats2half2_rn(v.z, v.w);
    return h;
}
__device__ __forceinline__ float4 unpack4(H4 h) {
    float2 l = __half22float2(h.lo), u = __half22float2(h.hi);
    return make_float4(l.x, l.y, u.x, u.y);
}
__device__ __forceinline__ float4 f4add(float4 a, float4 b) {
    return make_float4(a.x + b.x, a.y + b.y, a.z + b.z, a.w + b.w);
}
__device__ __forceinline__ float4 f4sub(float4 a, float4 b) {
    return make_float4(a.x - b.x, a.y - b.y, a.z - b.z, a.w - b.w);
}
__device__ __forceinline__ float4 f4s(float4 a, float s) {
    return make_float4(a.x * s, a.y * s, a.z * s, a.w * s);
}
__device__ __forceinline__ float4 f4mul(float4 a, float4 b) {
    return make_float4(a.x * b.x, a.y * b.y, a.z * b.z, a.w * b.w);
}
__device__ __forceinline__ float4 shup4(float4 v, int d) {
    return make_float4(__shfl_up(v.x, d), __shfl_up(v.y, d), __shfl_up(v.z, d), __shfl_up(v.w, d));
}
// XCD-grouping band swizzle (NB % 8 == 0 -> bijective).
__device__ __forceinline__ int band_of(int bx, int nbands) {
    return (bx & 7) * (nbands >> 3) + (bx >> 3);
}

// Block-wide inclusive prefix of 4 fields (2 float4/thread) into swizzled
// planes pl[f][idx4(p)], pl[f][idx4(0)] = 0. 2 internal syncs.
__device__ __forceinline__ void scan4(
    float4 (*pl)[PFXN], float4 (*wtot)[4],
    const float4* s0, const float4* s1, const float4* s2, const float4* s3,
    int t, int lane, int wv)
{
    const float4 z4 = make_float4(0.f, 0.f, 0.f, 0.f);
    float4 p0[2], p1[2], p2[2], p3[2];
    p0[0] = s0[0]; p1[0] = s1[0]; p2[0] = s2[0]; p3[0] = s3[0];
    p0[1] = f4add(p0[0], s0[1]); p1[1] = f4add(p1[0], s1[1]);
    p2[1] = f4add(p2[0], s2[1]); p3[1] = f4add(p3[0], s3[1]);
    float4 i0 = p0[1], i1 = p1[1], i2 = p2[1], i3 = p3[1];
    #pragma unroll
    for (int d = 1; d < 64; d <<= 1) {
        float4 t0 = shup4(i0, d), t1 = shup4(i1, d), t2 = shup4(i2, d), t3 = shup4(i3, d);
        if (lane >= d) {
            i0 = f4add(i0, t0); i1 = f4add(i1, t1);
            i2 = f4add(i2, t2); i3 = f4add(i3, t3);
        }
    }
    float4 e0 = shup4(i0, 1), e1 = shup4(i1, 1), e2 = shup4(i2, 1), e3 = shup4(i3, 1);
    if (lane == 0) { e0 = z4; e1 = z4; e2 = z4; e3 = z4; }
    if (lane == 63) { wtot[wv][0] = i0; wtot[wv][1] = i1; wtot[wv][2] = i2; wtot[wv][3] = i3; }
    __syncthreads();
    for (int wq = 0; wq < wv; ++wq) {
        e0 = f4add(e0, wtot[wq][0]); e1 = f4add(e1, wtot[wq][1]);
        e2 = f4add(e2, wtot[wq][2]); e3 = f4add(e3, wtot[wq][3]);
    }
    if (t == 0) {
        pl[0][idx4(0)] = z4; pl[1][idx4(0)] = z4;
        pl[2][idx4(0)] = z4; pl[3][idx4(0)] = z4;
    }
    #pragma unroll
    for (int i = 0; i < 2; ++i) {
        int p = 2 * t + 1 + i;
        pl[0][idx4(p)] = f4add(e0, p0[i]);
        pl[1][idx4(p)] = f4add(e1, p1[i]);
        pl[2][idx4(p)] = f4add(e2, p2[i]);
        pl[3][idx4(p)] = f4add(e3, p3[i]);
    }
    __syncthreads();
}

// Same for 2 fields.
__device__ __forceinline__ void scan2s(
    float4 (*pl)[PFXN], float4 (*wtot)[2],
    const float4* s0, const float4* s1, int t, int lane, int wv)
{
    const float4 z4 = make_float4(0.f, 0.f, 0.f, 0.f);
    float4 p0[2], p1[2];
    p0[0] = s0[0]; p1[0] = s1[0];
    p0[1] = f4add(p0[0], s0[1]); p1[1] = f4add(p1[0], s1[1]);
    float4 i0 = p0[1], i1 = p1[1];
    #pragma unroll
    for (int d = 1; d < 64; d <<= 1) {
        float4 t0 = shup4(i0, d), t1 = shup4(i1, d);
        if (lane >= d) { i0 = f4add(i0, t0); i1 = f4add(i1, t1); }
    }
    float4 e0 = shup4(i0, 1), e1 = shup4(i1, 1);
    if (lane == 0) { e0 = z4; e1 = z4; }
    if (lane == 63) { wtot[wv][0] = i0; wtot[wv][1] = i1; }
    __syncthreads();
    for (int wq = 0; wq < wv; ++wq) {
        e0 = f4add(e0, wtot[wq][0]); e1 = f4add(e1, wtot[wq][1]);
    }
    if (t == 0) { pl[0][idx4(0)] = z4; pl[1][idx4(0)] = z4; }
    #pragma unroll
    for (int i = 0; i < 2; ++i) {
        int p = 2 * t + 1 + i;
        pl[0][idx4(p)] = f4add(e0, p0[i]);
        pl[1][idx4(p)] = f4add(e1, p1[i]);
    }
    __syncthreads();
}

// ---------------- KA: I,p -> A,b (fp16) ----------------
__global__ __launch_bounds__(TPB, 2) void kfusedAB(
    const float4* __restrict__ I4, const float4* __restrict__ P4,
    H4* __restrict__ Aout, H4* __restrict__ Bout,
    const int* __restrict__ rptr)
{
    __shared__ float4 Pfx[4][PFXN];       // 73.8 KB, swizzled planes
    __shared__ float4 wtot[8][4];
    const int r = *rptr;
    const int t = threadIdx.x, lane = t & 63, wv = t >> 6;
    const int h0 = band_of(blockIdx.x, gridDim.x) * BH;
    const size_t imgb = (size_t)blockIdx.y * IMG4;
    const float4* Ib = I4 + imgb + 2 * t;
    const float4* Pb = P4 + imgb + 2 * t;
    H4* Ao = Aout + imgb;
    H4* Bo = Bout + imgb;
    const float4 z4 = make_float4(0.f, 0.f, 0.f, 0.f);

    float4 sI[2], sp[2], sIp[2], sII[2];
    #pragma unroll
    for (int i = 0; i < 2; ++i) { sI[i] = z4; sp[i] = z4; sIp[i] = z4; sII[i] = z4; }

    int lo = h0 - r; if (lo < 0) lo = 0;
    int hi = h0 + r; if (hi > HD - 1) hi = HD - 1;
    // warm-up, 4 rows batched for MLP
    int j = lo;
    for (; j + 3 <= hi; j += 4) {
        float4 a[4][2], c[4][2];
        #pragma unroll
        for (int k = 0; k < 4; ++k) {
            const float4* Ir = Ib + (size_t)(j + k) * ROW4;
            const float4* Pr = Pb + (size_t)(j + k) * ROW4;
            #pragma unroll
            for (int i = 0; i < 2; ++i) { a[k][i] = Ir[i]; c[k][i] = Pr[i]; }
        }
        #pragma unroll
        for (int k = 0; k < 4; ++k)
            #pragma unroll
            for (int i = 0; i < 2; ++i) {
                sI[i] = f4add(sI[i], a[k][i]);
                sp[i] = f4add(sp[i], c[k][i]);
                sIp[i].x += a[k][i].x * c[k][i].x; sIp[i].y += a[k][i].y * c[k][i].y;
                sIp[i].z += a[k][i].z * c[k][i].z; sIp[i].w += a[k][i].w * c[k][i].w;
                sII[i].x += a[k][i].x * a[k][i].x; sII[i].y += a[k][i].y * a[k][i].y;
                sII[i].z += a[k][i].z * a[k][i].z; sII[i].w += a[k][i].w * a[k][i].w;
            }
    }
    for (; j <= hi; ++j) {
        const float4* Ir = Ib + (size_t)j * ROW4;
        const float4* Pr = Pb + (size_t)j * ROW4;
        #pragma unroll
        for (int i = 0; i < 2; ++i) {
            float4 a = Ir[i], c = Pr[i];
            sI[i] = f4add(sI[i], a); sp[i] = f4add(sp[i], c);
            sIp[i].x += a.x*c.x; sIp[i].y += a.y*c.y; sIp[i].z += a.z*c.z; sIp[i].w += a.w*c.w;
            sII[i].x += a.x*a.x; sII[i].y += a.y*a.y; sII[i].z += a.z*a.z; sII[i].w += a.w*a.w;
        }
    }

    for (int hp = 0; hp < BH; hp += 2) {
        const int h = h0 + hp;
        // slide sets for h->h+1 (set0) and h+1->h+2 (set1); issue all loads now
        int ja0 = h + 1 + r, js0 = h - r;
        int ja1 = h + 2 + r, js1 = h + 1 - r;
        float wa0  = (ja0 <= HD - 1) ? 1.f : 0.f;
        float wsb0 = (js0 >= 0) ? 1.f : 0.f;
        float wa1  = (ja1 <= HD - 1) ? 1.f : 0.f;
        float wsb1 = (js1 >= 0) ? 1.f : 0.f;
        int jac0 = (ja0 <= HD - 1) ? ja0 : HD - 1;
        int jsc0 = (js0 >= 0) ? js0 : 0;
        int jac1 = (ja1 <= HD - 1) ? ja1 : HD - 1;
        int jsc1 = (js1 >= 0) ? js1 : 0;
        const float4* Ia0 = Ib + (size_t)jac0 * ROW4;
        const float4* Pa0 = Pb + (size_t)jac0 * ROW4;
        const float4* Is0 = Ib + (size_t)jsc0 * ROW4;
        const float4* Ps0 = Pb + (size_t)jsc0 * ROW4;
        const float4* Ia1 = Ib + (size_t)jac1 * ROW4;
        const float4* Pa1 = Pb + (size_t)jac1 * ROW4;
        const float4* Is1 = Ib + (size_t)jsc1 * ROW4;
        const float4* Ps1 = Pb + (size_t)jsc1 * ROW4;
        float4 A0a[2], C0a[2], A0s[2], C0s[2], A1a[2], C1a[2], A1s[2], C1s[2];
        #pragma unroll
        for (int i = 0; i < 2; ++i) {
            A0a[i] = Ia0[i]; C0a[i] = Pa0[i]; A0s[i] = Is0[i]; C0s[i] = Ps0[i];
            A1a[i] = Ia1[i]; C1a[i] = Pa1[i]; A1s[i] = Is1[i]; C1s[i] = Ps1[i];
        }

        #pragma unroll
        for (int sub = 0; sub < 2; ++sub) {
            const int hc = h + sub;
            int hl = hc - r; if (hl < 0) hl = 0;
            int hh = hc + r; if (hh > HD - 1) hh = HD - 1;
            const float cntH = (float)(hh - hl + 1);

            scan4(Pfx, wtot, sI, sp, sIp, sII, t, lane, wv);

            H4* Ar = Ao + (size_t)hc * ROW4;
            H4* Br = Bo + (size_t)hc * ROW4;
            #pragma unroll
            for (int i = 0; i < 2; ++i) {
                int wp = 2 * t + i;
                int wl = wp - r; if (wl < 0) wl = 0;
                int wh2 = wp + r; if (wh2 > WD - 1) wh2 = WD - 1;
                float invN = 1.f / ((float)(wh2 - wl + 1) * cntH);
                int iA = idx4(wh2 + 1), iB = idx4(wl);
                float4 mI  = f4s(f4sub(Pfx[0][iA], Pfx[0][iB]), invN);
                float4 mp  = f4s(f4sub(Pfx[1][iA], Pfx[1][iB]), invN);
                float4 mIp = f4s(f4sub(Pfx[2][iA], Pfx[2][iB]), invN);
                float4 mII = f4s(f4sub(Pfx[3][iA], Pfx[3][iB]), invN);
                float4 cov = f4sub(mIp, f4mul(mI, mp));
                float4 var = f4sub(mII, f4mul(mI, mI));
                float4 Av = make_float4(cov.x / (var.x + EPS), cov.y / (var.y + EPS),
                                        cov.z / (var.z + EPS), cov.w / (var.w + EPS));
                float4 Bv = f4sub(mp, f4mul(Av, mI));
                Ar[wp] = pack4(Av);
                Br[wp] = pack4(Bv);
            }
            __syncthreads();

            const float wa  = sub ? wa1 : wa0;
            const float wsb = sub ? wsb1 : wsb0;
            #pragma unroll
            for (int i = 0; i < 2; ++i) {
                float4 A1 = f4s(sub ? A1a[i] : A0a[i], wa);
                float4 C1 = f4s(sub ? C1a[i] : C0a[i], wa);
                float4 A2 = f4s(sub ? A1s[i] : A0s[i], wsb);
                float4 C2 = f4s(sub ? C1s[i] : C0s[i], wsb);
                sI[i] = f4add(f4sub(sI[i], A2), A1);
                sp[i] = f4add(f4sub(sp[i], C2), C1);
                sIp[i].x += A1.x*C1.x - A2.x*C2.x; sIp[i].y += A1.y*C1.y - A2.y*C2.y;
                sIp[i].z += A1.z*C1.z - A2.z*C2.z; sIp[i].w += A1.w*C1.w - A2.w*C2.w;
                sII[i].x += A1.x*A1.x - A2.x*A2.x; sII[i].y += A1.y*A1.y - A2.y*A2.y;
                sII[i].z += A1.z*A1.z - A2.z*A2.z; sII[i].w += A1.w*A1.w - A2.w*A2.w;
            }
        }
    }
}

// ---------------- KB: A,b -> q = meanA*I + meanb ----------------
__global__ __launch_bounds__(TPB, 2) void kfusedQ(
    const H4* __restrict__ Ain, const H4* __restrict__ Bin,
    const float4* __restrict__ I4, float4* __restrict__ Qout,
    const int* __restrict__ rptr)
{
    __shared__ float4 Pfx[2][PFXN];       // 36.9 KB
    __shared__ float4 wtot[8][2];
    const int r = *rptr;
    const int t = threadIdx.x, lane = t & 63, wv = t >> 6;
    const int h0 = band_of(blockIdx.x, gridDim.x) * BH;
    const size_t imgb = (size_t)blockIdx.y * IMG4;
    const H4* Abp = Ain + imgb + 2 * t;
    const H4* Bbp = Bin + imgb + 2 * t;
    const float4* Ib = I4 + imgb + 2 * t;
    float4* Qo = Qout + imgb;
    const float4 z4 = make_float4(0.f, 0.f, 0.f, 0.f);

    float4 sA[2], sB[2];
    #pragma unroll
    for (int i = 0; i < 2; ++i) { sA[i] = z4; sB[i] = z4; }

    int lo = h0 - r; if (lo < 0) lo = 0;
    int hi = h0 + r; if (hi > HD - 1) hi = HD - 1;
    // warm-up, 4 rows batched
    int j = lo;
    for (; j + 3 <= hi; j += 4) {
        H4 a[4][2], b[4][2];
        #pragma unroll
        for (int k = 0; k < 4; ++k) {
            const H4* Ar = Abp + (size_t)(j + k) * ROW4;
            const H4* Br = Bbp + (size_t)(j + k) * ROW4;
            #pragma unroll
            for (int i = 0; i < 2; ++i) { a[k][i] = Ar[i]; b[k][i] = Br[i]; }
        }
        #pragma unroll
        for (int k = 0; k < 4; ++k)
            #pragma unroll
            for (int i = 0; i < 2; ++i) {
                sA[i] = f4add(sA[i], unpack4(a[k][i]));
                sB[i] = f4add(sB[i], unpack4(b[k][i]));
            }
    }
    for (; j <= hi; ++j) {
        const H4* Ar = Abp + (size_t)j * ROW4;
        const H4* Br = Bbp + (size_t)j * ROW4;
        #pragma unroll
        for (int i = 0; i < 2; ++i) {
            sA[i] = f4add(sA[i], unpack4(Ar[i]));
            sB[i] = f4add(sB[i], unpack4(Br[i]));
        }
    }

    for (int hp = 0; hp < BH; hp += 2) {
        const int h = h0 + hp;
        int ja0 = h + 1 + r, js0 = h - r;
        int ja1 = h + 2 + r, js1 = h + 1 - r;
        float wa0  = (ja0 <= HD - 1) ? 1.f : 0.f;
        float wsb0 = (js0 >= 0) ? 1.f : 0.f;
        float wa1  = (ja1 <= HD - 1) ? 1.f : 0.f;
        float wsb1 = (js1 >= 0) ? 1.f : 0.f;
        int jac0 = (ja0 <= HD - 1) ? ja0 : HD - 1;
        int jsc0 = (js0 >= 0) ? js0 : 0;
        int jac1 = (ja1 <= HD - 1) ? ja1 : HD - 1;
        int jsc1 = (js1 >= 0) ? js1 : 0;
        H4 A0a[2], B0a[2], A0s[2], B0s[2], A1a[2], B1a[2], A1s[2], B1s[2];
        float4 iv0[2], iv1[2];
        {
            const H4* Aa0 = Abp + (size_t)jac0 * ROW4;
            const H4* Ba0 = Bbp + (size_t)jac0 * ROW4;
            const H4* As0 = Abp + (size_t)jsc0 * ROW4;
            const H4* Bs0 = Bbp + (size_t)jsc0 * ROW4;
            const H4* Aa1 = Abp + (size_t)jac1 * ROW4;
            const H4* Ba1 = Bbp + (size_t)jac1 * ROW4;
            const H4* As1 = Abp + (size_t)jsc1 * ROW4;
            const H4* Bs1 = Bbp + (size_t)jsc1 * ROW4;
            const float4* Ir0 = Ib + (size_t)h * ROW4;
            const float4* Ir1 = Ib + (size_t)(h + 1) * ROW4;
            #pragma unroll
            for (int i = 0; i < 2; ++i) {
                A0a[i] = Aa0[i]; B0a[i] = Ba0[i]; A0s[i] = As0[i]; B0s[i] = Bs0[i];
                A1a[i] = Aa1[i]; B1a[i] = Ba1[i]; A1s[i] = As1[i]; B1s[i] = Bs1[i];
                iv0[i] = Ir0[i]; iv1[i] = Ir1[i];
            }
        }

        #pragma unroll
        for (int sub = 0; sub < 2; ++sub) {
            const int hc = h + sub;
            int hl = hc - r; if (hl < 0) hl = 0;
            int hh = hc + r; if (hh > HD - 1) hh = HD - 1;
            const float cntH = (float)(hh - hl + 1);

            scan2s(Pfx, wtot, sA, sB, t, lane, wv);

            float4* Qrow = Qo + (size_t)hc * ROW4;
            #pragma unroll
            for (int i = 0; i < 2; ++i) {
                int wp = 2 * t + i;
                int wl = wp - r; if (wl < 0) wl = 0;
                int wh2 = wp + r; if (wh2 > WD - 1) wh2 = WD - 1;
                float invN = 1.f / ((float)(wh2 - wl + 1) * cntH);
                int iA = idx4(wh2 + 1), iB = idx4(wl);
                float4 mA = f4s(f4sub(Pfx[0][iA], Pfx[0][iB]), invN);
                float4 mB = f4s(f4sub(Pfx[1][iA], Pfx[1][iB]), invN);
                float4 iv = sub ? iv1[i] : iv0[i];
                Qrow[wp] = make_float4(mA.x * iv.x + mB.x, mA.y * iv.y + mB.y,
                                       mA.z * iv.z + mB.z, mA.w * iv.w + mB.w);
            }
            __syncthreads();

            const float wa  = sub ? wa1 : wa0;
            const float wsb = sub ? wsb1 : wsb0;
            #pragma unroll
            for (int i = 0; i < 2; ++i) {
                float4 A1 = f4s(unpack4(sub ? A1a[i] : A0a[i]), wa);
                float4 B1 = f4s(unpack4(sub ? B1a[i] : B0a[i]), wa);
                float4 A2 = f4s(unpack4(sub ? A1s[i] : A0s[i]), wsb);
                float4 B2 = f4s(unpack4(sub ? B1s[i] : B0s[i]), wsb);
                sA[i] = f4add(f4sub(sA[i], A2), A1);
                sB[i] = f4add(f4sub(sB[i], B2), B1);
            }
        }
    }
}

extern "C" void kernel_launch(void* const* d_in, const int* in_sizes, int n_in,
                              void* d_out, int out_size, void* d_ws, size_t ws_size,
                              hipStream_t stream)
{
    const float* I = (const float*)d_in[0];
    const float* P = (const float*)d_in[1];
    const int* rptr = (const int*)d_in[2];
    float* out = (float*)d_out;

    const int Bn = (int)(in_sizes[0] / IMGF);              // 4
    const size_t perBatch = 2 * IMG4 * sizeof(H4);         // A,b fp16 = 16 MiB

    int nbChunk = (int)(ws_size / perBatch);
    if (nbChunk < 1) nbChunk = 1;
    if (nbChunk > Bn) nbChunk = Bn;

    for (int b0 = 0; b0 < Bn; b0 += nbChunk) {
        const int nb = (b0 + nbChunk <= Bn) ? nbChunk : (Bn - b0);
        H4* Ah = (H4*)d_ws;
        H4* Bh = Ah + (size_t)nb * IMG4;
        const float4* Ib = (const float4*)(I + (size_t)b0 * IMGF);
        const float4* Pb = (const float4*)(P + (size_t)b0 * IMGF);
        float4* ob = (float4*)(out + (size_t)b0 * IMGF);

        kfusedAB<<<dim3(NB, nb), TPB, 0, stream>>>(Ib, Pb, Ah, Bh, rptr);
        kfusedQ<<<dim3(NB, nb), TPB, 0, stream>>>(Ah, Bh, Ib, ob, rptr);
    }
}